// Round 1
// baseline (334.413 us; speedup 1.0000x reference)
//
#include <hip/hip_runtime.h>
#include <stdint.h>

#define BS 8
#define LQ 256
#define CHN 3
#define HH 192
#define WW 192
#define HW (HH*WW)   /* 36864 */
#define KK 16

// ---------- helpers ----------

// monotone mapping: float -> uint32 preserving total order (no NaNs here)
__device__ __forceinline__ uint32_t fkey(float f) {
    uint32_t u = __float_as_uint(f);
    uint32_t mask = (uint32_t)((int32_t)u >> 31) | 0x80000000u;
    return u ^ mask;
}

__device__ __forceinline__ unsigned long long umin64(unsigned long long a, unsigned long long b) {
    return a < b ? a : b;
}

// wave(64)-wide min of a u64, butterfly via two 32-bit shuffles
__device__ __forceinline__ unsigned long long wave_min_u64(unsigned long long v) {
    #pragma unroll
    for (int off = 32; off >= 1; off >>= 1) {
        uint32_t lo = (uint32_t)v, hi = (uint32_t)(v >> 32);
        lo = __shfl_xor(lo, off, 64);
        hi = __shfl_xor(hi, off, 64);
        unsigned long long o = ((unsigned long long)hi << 32) | lo;
        v = umin64(v, o);
    }
    return v;
}

// branchless sorted insert into ascending kept[16]; no-op if key >= kept[15]
__device__ __forceinline__ void insert16(unsigned long long (&kept)[KK], unsigned long long key) {
    #pragma unroll
    for (int j = KK - 1; j >= 1; --j) {
        unsigned long long a = kept[j - 1];
        unsigned long long mn = umin64(kept[j], key);
        kept[j] = (key < a) ? a : mn;
    }
    kept[0] = umin64(kept[0], key);
}

// ---------- kernel 1: pooled colors per (b,l) ----------
__global__ __launch_bounds__(256) void pooled_kernel(const float* __restrict__ pred,
                                                     const float* __restrict__ ref,
                                                     float4* __restrict__ pooled) {
    int t = blockIdx.x * 256 + threadIdx.x;   // t = b*256 + l
    int b = t >> 8;
    int l = t & 255;
    int i = l * BS + b;                        // scrambled flat grid row
    int b2 = i >> 8, l2 = i & 255;
    const float* pr = pred + ((b2 * 256 + l2) * 8);
    float x = pr[0], y = pr[1];
    float fx = rintf(__fsub_rn(__fmul_rn(x, 192.0f), 0.5f));
    float fy = rintf(__fsub_rn(__fmul_rn(y, 192.0f), 0.5f));
    int ix = (int)fx, iy = (int)fy;
    int inb = (ix >= 0 && ix < WW && iy >= 0 && iy < HH) ? 1 : 0;
    int ixc = min(max(ix, 0), WW - 1);
    int iyc = min(max(iy, 0), HH - 1);
    float m = (float)inb;
    const float* img = ref + b * CHN * HW + iyc * WW + ixc;
    float p0 = __fmul_rn(img[0], m);
    float p1 = __fmul_rn(img[HW], m);
    float p2 = __fmul_rn(img[2 * HW], m);
    float psq = __fadd_rn(__fadd_rn(__fmul_rn(p0, p0), __fmul_rn(p1, p1)), __fmul_rn(p2, p2));
    pooled[t] = make_float4(p0, p1, p2, psq);
}

// ---------- kernel 2: per-(b,l) top-16 smallest similar over all pixels ----------
__device__ __forceinline__ void proc_pixel(float r0, float r1, float r2, int p,
                                           float p0, float p1, float p2, float psq,
                                           unsigned long long (&kept)[KK],
                                           unsigned long long tau) {
    float rsq   = __fadd_rn(__fadd_rn(__fmul_rn(r0, r0), __fmul_rn(r1, r1)), __fmul_rn(r2, r2));
    float cross = __fadd_rn(__fadd_rn(__fmul_rn(r0, p0), __fmul_rn(r1, p1)), __fmul_rn(r2, p2));
    float sim   = __fadd_rn(__fsub_rn(rsq, __fmul_rn(2.0f, cross)), psq);
    unsigned long long key = ((unsigned long long)fkey(sim) << 32) | (uint32_t)p;
    if (key < tau) insert16(kept, key);
}

__global__ __launch_bounds__(256) void topk_kernel(const float* __restrict__ ref,
                                                   const float4* __restrict__ pooled,
                                                   uint32_t* __restrict__ topk) {
    int bl = blockIdx.x;          // b*256 + l
    int b = bl >> 8;
    float4 pq = pooled[bl];
    const float4* img0 = (const float4*)(ref + (size_t)b * CHN * HW);
    const float4* img1 = (const float4*)(ref + (size_t)b * CHN * HW + HW);
    const float4* img2 = (const float4*)(ref + (size_t)b * CHN * HW + 2 * HW);

    unsigned long long kept[KK];
    #pragma unroll
    for (int j = 0; j < KK; ++j) kept[j] = ~0ull;
    unsigned long long tau = ~0ull;

    // 36864 pixels / (256 threads * 4 px) = 36 iterations
    for (int it = 0; it < HW / (256 * 4); ++it) {
        int vid = it * 256 + threadIdx.x;     // float4 index, coalesced
        float4 a = img0[vid];
        float4 c1 = img1[vid];
        float4 c2 = img2[vid];
        int pbase = vid * 4;
        proc_pixel(a.x, c1.x, c2.x, pbase + 0, pq.x, pq.y, pq.z, pq.w, kept, tau);
        proc_pixel(a.y, c1.y, c2.y, pbase + 1, pq.x, pq.y, pq.z, pq.w, kept, tau);
        proc_pixel(a.z, c1.z, c2.z, pbase + 2, pq.x, pq.y, pq.z, pq.w, kept, tau);
        proc_pixel(a.w, c1.w, c2.w, pbase + 3, pq.x, pq.y, pq.z, pq.w, kept, tau);
        if ((it & 3) == 3) {
            tau = wave_min_u64(kept[KK - 1]);   // sound prune threshold (>= global 16th)
        }
    }

    // --- wave-level merge: 16 rounds of min-pop ---
    __shared__ unsigned long long smerge[4 * KK];
    int wid = threadIdx.x >> 6;
    int lane = threadIdx.x & 63;
    #pragma unroll 1
    for (int r = 0; r < KK; ++r) {
        unsigned long long h = kept[0];
        unsigned long long m = wave_min_u64(h);
        if (h == m) {                          // unique key -> exactly one lane pops
            #pragma unroll
            for (int j = 0; j < KK - 1; ++j) kept[j] = kept[j + 1];
            kept[KK - 1] = ~0ull;
        }
        if (lane == 0) smerge[wid * KK + r] = m;
    }
    __syncthreads();

    // --- block-level 4-way merge of sorted lists, thread 0 ---
    if (threadIdx.x == 0) {
        int h0 = 0, h1 = 0, h2 = 0, h3 = 0;
        uint32_t* out = topk + (size_t)bl * KK;
        for (int r = 0; r < KK; ++r) {
            unsigned long long c0 = h0 < KK ? smerge[0 * KK + h0] : ~0ull;
            unsigned long long c1 = h1 < KK ? smerge[1 * KK + h1] : ~0ull;
            unsigned long long c2 = h2 < KK ? smerge[2 * KK + h2] : ~0ull;
            unsigned long long c3 = h3 < KK ? smerge[3 * KK + h3] : ~0ull;
            unsigned long long m = umin64(umin64(c0, c1), umin64(c2, c3));
            if (m == c0) h0++;
            else if (m == c1) h1++;
            else if (m == c2) h2++;
            else h3++;
            out[r] = (uint32_t)m;              // pixel index, ascending-similar order
        }
    }
}

// ---------- kernel 3: argmin over rolled targets + loss partials ----------
__global__ __launch_bounds__(256) void loss_kernel(const float* __restrict__ pred,
                                                   const uint32_t* __restrict__ topk,
                                                   double* __restrict__ partial) {
    int t = blockIdx.x * 256 + threadIdx.x;   // t = b*256 + l
    int b = t >> 8;
    int l = t & 255;
    float px = pred[(size_t)t * 8 + 0];
    float py = pred[(size_t)t * 8 + 1];
    int lp = (l + LQ - 1) & (LQ - 1);         // roll(shift=1): row l reads tgt[l-1]
    const uint32_t* id = topk + ((size_t)(b * 256 + lp)) * KK;
    float best_d = __int_as_float(0x7f800000); // +inf
    float bx = 0.0f, by = 0.0f;
    #pragma unroll
    for (int k = 0; k < KK; ++k) {
        uint32_t idx = id[k];
        float tx = (float)(idx % WW) / 192.0f;
        float ty = (float)(idx / WW) / 192.0f;
        float dx = __fsub_rn(px, tx);
        float dy = __fsub_rn(py, ty);
        float d = __fadd_rn(__fmul_rn(dx, dx), __fmul_rn(dy, dy));
        if (d < best_d) { best_d = d; bx = tx; by = ty; }  // first-min = argmin
    }
    float term = 0.0f;
    if (l >= 1) {
        float ex = __fsub_rn(px, bx);
        float ey = __fsub_rn(py, by);
        term = __fadd_rn(__fmul_rn(ex, ex), __fmul_rn(ey, ey));
    }
    __shared__ double sred[256];
    sred[threadIdx.x] = (double)term;
    __syncthreads();
    for (int s = 128; s > 0; s >>= 1) {
        if (threadIdx.x < s) sred[threadIdx.x] += sred[threadIdx.x + s];
        __syncthreads();
    }
    if (threadIdx.x == 0) partial[blockIdx.x] = sred[0];
}

// ---------- kernel 4: finalize mean ----------
__global__ void finalize_kernel(const double* __restrict__ partial, float* __restrict__ out) {
    if (threadIdx.x == 0 && blockIdx.x == 0) {
        double s = 0.0;
        for (int i = 0; i < BS; ++i) s += partial[i];
        out[0] = (float)(s / 2040.0);   // mean over bs*(L-1) = 8*255
    }
}

// ---------- launch ----------
extern "C" void kernel_launch(void* const* d_in, const int* in_sizes, int n_in,
                              void* d_out, int out_size, void* d_ws, size_t ws_size,
                              hipStream_t stream) {
    const float* pred = (const float*)d_in[0];   // (8,256,8) f32
    const float* ref  = (const float*)d_in[1];   // (8,3,192,192) f32
    float* out = (float*)d_out;

    char* ws = (char*)d_ws;
    float4*   pooled  = (float4*)ws;                              // 2048*16B = 32 KB
    uint32_t* topk    = (uint32_t*)(ws + 2048 * 16);              // 2048*16*4B = 128 KB
    double*   partial = (double*)(ws + 2048 * 16 + 2048 * KK * 4); // 8*8B

    pooled_kernel  <<<BS, 256, 0, stream>>>(pred, ref, pooled);
    topk_kernel    <<<BS * LQ, 256, 0, stream>>>(ref, pooled, topk);
    loss_kernel    <<<BS, 256, 0, stream>>>(pred, topk, partial);
    finalize_kernel<<<1, 64, 0, stream>>>(partial, out);
}